// Round 1
// baseline (507.144 us; speedup 1.0000x reference)
//
#include <hip/hip_runtime.h>
#include <stdint.h>

#define Bn 4
#define Sn 2048
#define En 1024
#define Hn 16
#define HDn 64

typedef __bf16 bf16;
typedef __bf16 bf16x4 __attribute__((ext_vector_type(4)));
typedef __bf16 bf16x8 __attribute__((ext_vector_type(8)));
typedef float  f32x4  __attribute__((ext_vector_type(4)));

// async global->LDS, 16B per lane, dest = wave-uniform base + lane*16
#define GLDS(gp, lp) __builtin_amdgcn_global_load_lds( \
    (const __attribute__((address_space(1))) void*)(gp), \
    (__attribute__((address_space(3))) void*)(lp), 16, 0, 0)

__global__ __launch_bounds__(256) void cvt_f32_to_bf16(
    const float* __restrict__ in, bf16* __restrict__ out, int n4)
{
    int i = blockIdx.x * 256 + threadIdx.x;
    if (i >= n4) return;
    float4 f = reinterpret_cast<const float4*>(in)[i];
    bf16x4 o;
    o[0] = (bf16)f.x; o[1] = (bf16)f.y; o[2] = (bf16)f.z; o[3] = (bf16)f.w;
    reinterpret_cast<bf16x4*>(out)[i] = o;
}

// C = A (MxK) * B^T where Bw is (NxK) row-major. bf16 in, fp32 accum.
// MODE 0: scatter epilogue -> Q/K/V (B,H,S,HD) bf16
// MODE 1: C fp32 + bias
template<int MODE>
__global__ __launch_bounds__(256) void gemm_bt(
    const bf16* __restrict__ A, const bf16* __restrict__ Bw,
    int M, int N, int K,
    bf16* __restrict__ q_out, bf16* __restrict__ k_out, bf16* __restrict__ v_out,
    float* __restrict__ c_out, const float* __restrict__ bias)
{
    __shared__ bf16 lA[128*64];
    __shared__ bf16 lB[128*64];
    const int tid  = threadIdx.x;
    const int lane = tid & 63;
    const int wv   = tid >> 6;
    const int wm = wv >> 1, wn = wv & 1;
    const int m0 = blockIdx.y * 128;
    const int n0 = blockIdx.x * 128;
    const int lr = lane & 15, lg = lane >> 4;

    f32x4 acc[4][4] = {};

    const int rowA = wv*8 + (lane>>3);   // staging row within 32-row chunk
    const int col8 = (lane&7)*8;         // staging col (bf16 elems)

    for (int k0 = 0; k0 < K; k0 += 64) {
        #pragma unroll
        for (int c = 0; c < 4; ++c) {
            int row = c*32 + rowA;
            GLDS(A  + (size_t)(m0+row)*K + k0 + col8, lA + (c*32 + wv*8)*64);
            GLDS(Bw + (size_t)(n0+row)*K + k0 + col8, lB + (c*32 + wv*8)*64);
        }
        __syncthreads();
        #pragma unroll
        for (int kk = 0; kk < 64; kk += 32) {
            bf16x8 af[4], bfv[4];
            #pragma unroll
            for (int i = 0; i < 4; ++i)
                af[i] = *reinterpret_cast<const bf16x8*>(lA + (wm*64 + i*16 + lr)*64 + kk + lg*8);
            #pragma unroll
            for (int j = 0; j < 4; ++j)
                bfv[j] = *reinterpret_cast<const bf16x8*>(lB + (wn*64 + j*16 + lr)*64 + kk + lg*8);
            #pragma unroll
            for (int i = 0; i < 4; ++i)
                #pragma unroll
                for (int j = 0; j < 4; ++j)
                    acc[i][j] = __builtin_amdgcn_mfma_f32_16x16x32_bf16(af[i], bfv[j], acc[i][j], 0, 0, 0);
        }
        __syncthreads();
    }

    #pragma unroll
    for (int i = 0; i < 4; ++i) {
        #pragma unroll
        for (int j = 0; j < 4; ++j) {
            const int colb = n0 + wn*64 + j*16 + lr;
            #pragma unroll
            for (int r = 0; r < 4; ++r) {
                const int rowb = m0 + wm*64 + i*16 + lg*4 + r;
                const float v = acc[i][j][r];
                if (MODE == 0) {
                    const int b = rowb >> 11, s = rowb & (Sn-1);
                    const int h = colb / 192, rr = colb - h*192;
                    const int wq = rr >> 6, hd = rr & 63;
                    const size_t off = (((size_t)(b*Hn + h))*Sn + s)*HDn + hd;
                    const bf16 bv = (bf16)v;
                    if (wq == 0)      q_out[off] = bv;
                    else if (wq == 1) k_out[off] = bv;
                    else              v_out[off] = bv;
                } else {
                    c_out[(size_t)rowb*N + colb] = v + bias[colb];
                }
            }
        }
    }
}

// Flash attention, causal. Block = 4 waves, each wave owns 16 queries.
// KV tiles of 32 keys shared in LDS (K swizzled, V transposed+padded).
__global__ __launch_bounds__(256) void attn_fwd(
    const bf16* __restrict__ Q, const bf16* __restrict__ Kg, const bf16* __restrict__ Vg,
    bf16* __restrict__ O)
{
    __shared__ bf16 Kl[32*64];      // [key][hd], rows XOR-swizzled at 16B granularity
    __shared__ bf16 Vt[64*48];      // [hd][key], padded stride 48
    __shared__ bf16 Pl[4][16*48];   // per-wave P, padded stride 48

    const int tid  = threadIdx.x;
    const int lane = tid & 63;
    const int w    = tid >> 6;
    const int lr = lane & 15, lg = lane >> 4;
    const int bh = blockIdx.y;
    const int b  = bh >> 4, h = bh & (Hn-1);
    const int qt = blockIdx.x;
    const int q0 = qt*64 + w*16;

    const bf16* Qb = Q  + (size_t)bh*Sn*HDn;
    const bf16* Kb = Kg + (size_t)bh*Sn*HDn;
    const bf16* Vb = Vg + (size_t)bh*Sn*HDn;

    // Q fragments in registers: A-frag m=lr, k(hd) = c*32 + lg*8 + j
    bf16x8 aq[2];
    #pragma unroll
    for (int c = 0; c < 2; ++c)
        aq[c] = *reinterpret_cast<const bf16x8*>(Qb + (size_t)(q0 + lr)*HDn + c*32 + lg*8);

    f32x4 o[4] = {};
    float m4[4], l4[4];
    #pragma unroll
    for (int r = 0; r < 4; ++r) { m4[r] = -1e30f; l4[r] = 0.f; }

    bf16* Plw = Pl[w];
    const int nkt = 2*qt + 2;

    const int skey = tid >> 3;              // 0..31 staging key
    const int scc  = tid & 7;               // 16B chunk within 128B row
    const int scs  = scc ^ (skey & 7);      // pre-swizzled global chunk

    for (int kt = 0; kt < nkt; ++kt) {
        const int k0 = kt*32;
        __syncthreads();   // previous tile fully consumed
        // stage K: LDS linear, global source pre-swizzled (m173 pattern)
        GLDS(Kb + (size_t)(k0 + skey)*HDn + scs*8, Kl + w*512);
        // stage V transposed into [hd][key] (stride 48)
        {
            bf16x8 vv = *reinterpret_cast<const bf16x8*>(Vb + (size_t)(k0 + skey)*HDn + scc*8);
            #pragma unroll
            for (int j = 0; j < 8; ++j)
                Vt[(scc*8 + j)*48 + skey] = vv[j];
        }
        __syncthreads();

        // S = Q * K^T  (two 16-key column blocks, two hd chunks each)
        f32x4 sc[2] = {};
        #pragma unroll
        for (int nb = 0; nb < 2; ++nb) {
            const int key = nb*16 + lr;
            #pragma unroll
            for (int c = 0; c < 2; ++c) {
                const int chunk = (c*4 + lg) ^ (key & 7);
                bf16x8 bk = *reinterpret_cast<const bf16x8*>(
                    reinterpret_cast<const char*>(Kl) + key*128 + chunk*16);
                sc[nb] = __builtin_amdgcn_mfma_f32_16x16x32_bf16(aq[c], bk, sc[nb], 0, 0, 0);
            }
        }

        // online softmax; D layout: col(key)=lr, row(q)=lg*4+r
        #pragma unroll
        for (int r = 0; r < 4; ++r) {
            const int qg = q0 + lg*4 + r;
            float s0 = sc[0][r] * 0.125f;
            float s1 = sc[1][r] * 0.125f;
            if (k0 + lr      > qg) s0 = -1e30f;
            if (k0 + 16 + lr > qg) s1 = -1e30f;
            float t = fmaxf(s0, s1);
            #pragma unroll
            for (int d = 1; d < 16; d <<= 1) t = fmaxf(t, __shfl_xor(t, d));
            const float mn = fmaxf(m4[r], t);
            const float fr = __expf(m4[r] - mn);
            m4[r] = mn;
            const float p0 = __expf(s0 - mn);
            const float p1 = __expf(s1 - mn);
            float rs = p0 + p1;
            #pragma unroll
            for (int d = 1; d < 16; d <<= 1) rs += __shfl_xor(rs, d);
            l4[r] = l4[r]*fr + rs;
            #pragma unroll
            for (int hb = 0; hb < 4; ++hb) o[hb][r] *= fr;
            const int row = lg*4 + r;
            Plw[row*48 + lr]      = (bf16)p0;
            Plw[row*48 + 16 + lr] = (bf16)p1;
        }

        // O += P * V   (A-frag from Plw, B-frag from Vt)
        bf16x8 pa = *reinterpret_cast<const bf16x8*>(Plw + lr*48 + lg*8);
        #pragma unroll
        for (int hb = 0; hb < 4; ++hb) {
            bf16x8 vb = *reinterpret_cast<const bf16x8*>(Vt + (hb*16 + lr)*48 + lg*8);
            o[hb] = __builtin_amdgcn_mfma_f32_16x16x32_bf16(pa, vb, o[hb], 0, 0, 0);
        }
    }

    // epilogue: O layout col(hd)=lr, row(q)=lg*4+r ; write (b,s,h*64+hd) bf16
    #pragma unroll
    for (int hb = 0; hb < 4; ++hb) {
        #pragma unroll
        for (int r = 0; r < 4; ++r) {
            const int qg = q0 + lg*4 + r;
            O[((size_t)(b*Sn + qg))*En + h*HDn + hb*16 + lr] = (bf16)(o[hb][r] / l4[r]);
        }
    }
}

extern "C" void kernel_launch(void* const* d_in, const int* in_sizes, int n_in,
                              void* d_out, int out_size, void* d_ws, size_t ws_size,
                              hipStream_t stream)
{
    (void)in_sizes; (void)n_in; (void)out_size; (void)ws_size;
    const float* x    = (const float*)d_in[0];
    const float* Wqkv = (const float*)d_in[1];
    const float* Wo   = (const float*)d_in[2];
    const float* bo   = (const float*)d_in[3];
    float* out = (float*)d_out;

    const size_t nBS = (size_t)Bn*Sn;          // 8192 rows
    char* ws = (char*)d_ws;
    bf16* xb    = (bf16*)ws; ws += nBS*En*2;            // 16 MB
    bf16* wqkvb = (bf16*)ws; ws += (size_t)3*En*En*2;   // 6 MB
    bf16* wob   = (bf16*)ws; ws += (size_t)En*En*2;     // 2 MB
    bf16* Qb    = (bf16*)ws; ws += nBS*En*2;            // 16 MB
    bf16* Kb    = (bf16*)ws; ws += nBS*En*2;            // 16 MB
    bf16* Vb    = (bf16*)ws; ws += nBS*En*2;            // 16 MB
    bf16* AO    = (bf16*)ws; ws += nBS*En*2;            // 16 MB

    int n4 = (int)(nBS*En/4);
    cvt_f32_to_bf16<<<(n4+255)/256, 256, 0, stream>>>(x, xb, n4);
    n4 = 3*En*En/4;
    cvt_f32_to_bf16<<<(n4+255)/256, 256, 0, stream>>>(Wqkv, wqkvb, n4);
    n4 = En*En/4;
    cvt_f32_to_bf16<<<(n4+255)/256, 256, 0, stream>>>(Wo, wob, n4);

    gemm_bt<0><<<dim3(3*En/128, nBS/128), 256, 0, stream>>>(
        xb, wqkvb, (int)nBS, 3*En, En, Qb, Kb, Vb, nullptr, nullptr);

    attn_fwd<<<dim3(Sn/64, Bn*Hn), 256, 0, stream>>>(Qb, Kb, Vb, AO);

    gemm_bt<1><<<dim3(En/128, nBS/128), 256, 0, stream>>>(
        AO, wob, (int)nBS, En, En, nullptr, nullptr, nullptr, out, bo);
}

// Round 2
// 205.511 us; speedup vs baseline: 2.4677x; 2.4677x over previous
//
#include <hip/hip_runtime.h>
#include <stdint.h>

#define Bn 4
#define Sn 2048
#define En 1024
#define Hn 16
#define HDn 64

typedef __bf16 bf16;
typedef __bf16 bf16x4 __attribute__((ext_vector_type(4)));
typedef __bf16 bf16x8 __attribute__((ext_vector_type(8)));
typedef float  f32x4  __attribute__((ext_vector_type(4)));
typedef float  f32x16 __attribute__((ext_vector_type(16)));
typedef uint32_t u32x4 __attribute__((ext_vector_type(4)));

// async global->LDS, 16B per lane, dest = wave-uniform base + lane*16
#define GLDS(gp, lp) __builtin_amdgcn_global_load_lds( \
    (const __attribute__((address_space(1))) void*)(gp), \
    (__attribute__((address_space(3))) void*)(lp), 16, 0, 0)

__global__ __launch_bounds__(256) void cvt_f32_to_bf16(
    const float* __restrict__ in, bf16* __restrict__ out, int n4)
{
    int i = blockIdx.x * 256 + threadIdx.x;
    if (i >= n4) return;
    float4 f = reinterpret_cast<const float4*>(in)[i];
    bf16x4 o;
    o[0] = (bf16)f.x; o[1] = (bf16)f.y; o[2] = (bf16)f.z; o[3] = (bf16)f.w;
    reinterpret_cast<bf16x4*>(out)[i] = o;
}

// C = A (MxK) * B^T where Bw is (NxK) row-major. bf16 in, fp32 accum.
template<int MODE>
__global__ __launch_bounds__(256) void gemm_bt(
    const bf16* __restrict__ A, const bf16* __restrict__ Bw,
    int M, int N, int K,
    bf16* __restrict__ q_out, bf16* __restrict__ k_out, bf16* __restrict__ v_out,
    float* __restrict__ c_out, const float* __restrict__ bias)
{
    __shared__ bf16 lA[128*64];
    __shared__ bf16 lB[128*64];
    const int tid  = threadIdx.x;
    const int lane = tid & 63;
    const int wv   = tid >> 6;
    const int wm = wv >> 1, wn = wv & 1;
    const int m0 = blockIdx.y * 128;
    const int n0 = blockIdx.x * 128;
    const int lr = lane & 15, lg = lane >> 4;

    f32x4 acc[4][4] = {};

    const int rowA = wv*8 + (lane>>3);
    const int col8 = (lane&7)*8;

    for (int k0 = 0; k0 < K; k0 += 64) {
        #pragma unroll
        for (int c = 0; c < 4; ++c) {
            int row = c*32 + rowA;
            GLDS(A  + (size_t)(m0+row)*K + k0 + col8, lA + (c*32 + wv*8)*64);
            GLDS(Bw + (size_t)(n0+row)*K + k0 + col8, lB + (c*32 + wv*8)*64);
        }
        __syncthreads();
        #pragma unroll
        for (int kk = 0; kk < 64; kk += 32) {
            bf16x8 af[4], bfv[4];
            #pragma unroll
            for (int i = 0; i < 4; ++i)
                af[i] = *reinterpret_cast<const bf16x8*>(lA + (wm*64 + i*16 + lr)*64 + kk + lg*8);
            #pragma unroll
            for (int j = 0; j < 4; ++j)
                bfv[j] = *reinterpret_cast<const bf16x8*>(lB + (wn*64 + j*16 + lr)*64 + kk + lg*8);
            #pragma unroll
            for (int i = 0; i < 4; ++i)
                #pragma unroll
                for (int j = 0; j < 4; ++j)
                    acc[i][j] = __builtin_amdgcn_mfma_f32_16x16x32_bf16(af[i], bfv[j], acc[i][j], 0, 0, 0);
        }
        __syncthreads();
    }

    #pragma unroll
    for (int i = 0; i < 4; ++i) {
        #pragma unroll
        for (int j = 0; j < 4; ++j) {
            const int colb = n0 + wn*64 + j*16 + lr;
            #pragma unroll
            for (int r = 0; r < 4; ++r) {
                const int rowb = m0 + wm*64 + i*16 + lg*4 + r;
                const float v = acc[i][j][r];
                if (MODE == 0) {
                    const int b = rowb >> 11, s = rowb & (Sn-1);
                    const int h = colb / 192, rr = colb - h*192;
                    const int wq = rr >> 6, hd = rr & 63;
                    const size_t off = (((size_t)(b*Hn + h))*Sn + s)*HDn + hd;
                    const bf16 bv = (bf16)v;
                    if (wq == 0)      q_out[off] = bv;
                    else if (wq == 1) k_out[off] = bv;
                    else              v_out[off] = bv;
                } else {
                    c_out[(size_t)rowb*N + colb] = v + bias[colb];
                }
            }
        }
    }
}

static __device__ __forceinline__ uint32_t pkbf(float lo, float hi)
{
    uint16_t a = __builtin_bit_cast(uint16_t, (bf16)lo);
    uint16_t b = __builtin_bit_cast(uint16_t, (bf16)hi);
    return (uint32_t)a | ((uint32_t)b << 16);
}

// Flash attention, causal. 8 waves x 32 queries, KV tiles of 64 keys.
// Swapped QK^T (S^T in regs, lane col = query) -> in-register softmax.
// O kept transposed (O^T = V^T P^T) so rescale is per-lane scalar.
__global__ __launch_bounds__(512) void attn_fwd(
    const bf16* __restrict__ Q, const bf16* __restrict__ Kg, const bf16* __restrict__ Vg,
    bf16* __restrict__ O)
{
    __shared__ __align__(16) bf16 Kl[64*64];   // [key][hd], chunk ^= key&7
    __shared__ __align__(16) bf16 Vt[64*64];   // V^T subtiled: elem(hd,key) at chunk hd*8+((key>>3)^(hd>>3&7)), byte (key&7)*2

    const int tid  = threadIdx.x;
    const int lane = tid & 63;
    const int w    = tid >> 6;
    const int col  = lane & 31;   // query col (QK D) / hd col (PV A)
    const int hv   = lane >> 5;   // lane half
    const int bh   = blockIdx.x;
    const int qb   = (gridDim.y - 1) - blockIdx.y;   // heavy blocks dispatched first
    const int q0w  = qb*256 + w*32;
    const int qg   = q0w + col;

    const bf16* Qb = Q  + (size_t)bh*Sn*HDn;
    const bf16* Kb = Kg + (size_t)bh*Sn*HDn;
    const bf16* Vb = Vg + (size_t)bh*Sn*HDn;

    // Q B-fragments: B[k=hd][n=q]: lane holds q=col, hd = ks*16 + hv*8 + j
    bf16x8 aq[4];
    #pragma unroll
    for (int ks = 0; ks < 4; ++ks)
        aq[ks] = *reinterpret_cast<const bf16x8*>(Qb + (size_t)qg*HDn + ks*16 + hv*8);

    f32x16 ov[2] = {};
    float m_run = -1e30f, l_run = 0.f;

    const int srow = tid >> 3;               // staging row 0..63
    const int scol = tid & 7;                // 16B chunk in row
    const int ksw  = scol ^ (srow & 7);      // pre-swizzled K source chunk

    const int nkt = 4*(qb+1);
    for (int kt = 0; kt < nkt; ++kt) {
        const int k0 = kt*64;
        __syncthreads();   // previous tile consumed
        // stage K via global_load_lds (LDS linear, source pre-swizzled)
        GLDS(Kb + (size_t)(k0 + srow)*HDn + ksw*8, Kl + (size_t)w*512);
        // stage V^T (swizzled subtile layout; writes spread over all 8 bank columns)
        {
            bf16x8 vv = *reinterpret_cast<const bf16x8*>(Vb + (size_t)(k0 + srow)*HDn + scol*8);
            #pragma unroll
            for (int j = 0; j < 8; ++j) {
                const int chunk = (scol*8 + j)*8 + ((srow>>3) ^ scol);
                Vt[chunk*8 + (srow&7)] = vv[j];
            }
        }
        __syncthreads();

        if (k0 > q0w + 31) continue;   // tile fully masked for this wave (barriers done)

        // S^T = K * Q^T : D col = query, rows = keys
        f32x16 st[2] = {};
        #pragma unroll
        for (int kb = 0; kb < 2; ++kb) {
            const int key = kb*32 + col;
            #pragma unroll
            for (int ks = 0; ks < 4; ++ks) {
                const int chunk = key*8 + ((ks*2 + hv) ^ (key & 7));
                bf16x8 kf = *reinterpret_cast<const bf16x8*>(Kl + chunk*8);
                st[kb] = __builtin_amdgcn_mfma_f32_32x32x16_bf16(kf, aq[ks], st[kb], 0, 0, 0);
            }
        }

        // scale
        #pragma unroll
        for (int kb = 0; kb < 2; ++kb)
            #pragma unroll
            for (int r = 0; r < 16; ++r)
                st[kb][r] = st[kb][r] * 0.125f;

        // causal mask (only on diagonal tiles; wave-uniform branch)
        if (k0 + 63 > q0w) {
            #pragma unroll
            for (int kb = 0; kb < 2; ++kb)
                #pragma unroll
                for (int r = 0; r < 16; ++r) {
                    const int keyg = k0 + kb*32 + (r&3) + 8*(r>>2) + 4*hv;
                    if (keyg > qg) st[kb][r] = -1e30f;
                }
        }

        // in-register online softmax (per lane = per query; halves share via 1 shfl)
        float mx = st[0][0];
        #pragma unroll
        for (int kb = 0; kb < 2; ++kb)
            #pragma unroll
            for (int r = 0; r < 16; ++r)
                mx = fmaxf(mx, st[kb][r]);
        mx = fmaxf(mx, __shfl_xor(mx, 32));
        const float mn = fmaxf(m_run, mx);
        const float fr = __expf(m_run - mn);
        m_run = mn;

        uint32_t wpk[2][8];
        float sum = 0.f;
        #pragma unroll
        for (int kb = 0; kb < 2; ++kb)
            #pragma unroll
            for (int i = 0; i < 8; ++i) {
                const float e0 = __expf(st[kb][2*i]   - mn);
                const float e1 = __expf(st[kb][2*i+1] - mn);
                sum += e0 + e1;
                wpk[kb][i] = pkbf(e0, e1);
            }
        l_run = l_run*fr + sum;
        #pragma unroll
        for (int hb = 0; hb < 2; ++hb)
            #pragma unroll
            for (int r = 0; r < 16; ++r)
                ov[hb][r] *= fr;

        // O^T += V^T * P^T ; P^T B-frags assembled in-register (one half-swap shfl pair per step)
        #pragma unroll
        for (int s = 0; s < 4; ++s) {
            const int kb = s >> 1, ls = s & 1;
            const uint32_t send0 = hv ? wpk[kb][4*ls+0] : wpk[kb][4*ls+2];
            const uint32_t send1 = hv ? wpk[kb][4*ls+1] : wpk[kb][4*ls+3];
            const uint32_t keep0 = hv ? wpk[kb][4*ls+2] : wpk[kb][4*ls+0];
            const uint32_t keep1 = hv ? wpk[kb][4*ls+3] : wpk[kb][4*ls+1];
            const uint32_t r0 = (uint32_t)__shfl_xor((int)send0, 32);
            const uint32_t r1 = (uint32_t)__shfl_xor((int)send1, 32);
            u32x4 pwv = { hv ? r0 : keep0, hv ? r1 : keep1,
                          hv ? keep0 : r0, hv ? keep1 : r1 };
            bf16x8 pB = __builtin_bit_cast(bf16x8, pwv);
            #pragma unroll
            for (int hb = 0; hb < 2; ++hb) {
                const int hd = hb*32 + col;
                const int chunk = hd*8 + ((s*2 + hv) ^ ((hd>>3) & 7));
                bf16x8 vf = *reinterpret_cast<const bf16x8*>(Vt + chunk*8);
                ov[hb] = __builtin_amdgcn_mfma_f32_32x32x16_bf16(vf, pB, ov[hb], 0, 0, 0);
            }
        }
    }

    // epilogue: O^T col = query (lane), rows = hd; l split across halves
    const float lt  = l_run + __shfl_xor(l_run, 32);
    const float inv = 1.0f / lt;
    const int b = bh >> 4, hh = bh & 15;
    bf16* Ob = O + ((size_t)(b*Sn + qg))*En + hh*HDn;
    #pragma unroll
    for (int hb = 0; hb < 2; ++hb)
        #pragma unroll
        for (int g = 0; g < 4; ++g) {
            bf16x4 o4;
            #pragma unroll
            for (int r4 = 0; r4 < 4; ++r4)
                o4[r4] = (bf16)(ov[hb][g*4 + r4] * inv);
            *reinterpret_cast<bf16x4*>(Ob + hb*32 + g*8 + 4*hv) = o4;
        }
}

extern "C" void kernel_launch(void* const* d_in, const int* in_sizes, int n_in,
                              void* d_out, int out_size, void* d_ws, size_t ws_size,
                              hipStream_t stream)
{
    (void)in_sizes; (void)n_in; (void)out_size; (void)ws_size;
    const float* x    = (const float*)d_in[0];
    const float* Wqkv = (const float*)d_in[1];
    const float* Wo   = (const float*)d_in[2];
    const float* bo   = (const float*)d_in[3];
    float* out = (float*)d_out;

    const size_t nBS = (size_t)Bn*Sn;
    char* ws = (char*)d_ws;
    bf16* xb    = (bf16*)ws; ws += nBS*En*2;
    bf16* wqkvb = (bf16*)ws; ws += (size_t)3*En*En*2;
    bf16* wob   = (bf16*)ws; ws += (size_t)En*En*2;
    bf16* Qb    = (bf16*)ws; ws += nBS*En*2;
    bf16* Kb    = (bf16*)ws; ws += nBS*En*2;
    bf16* Vb    = (bf16*)ws; ws += nBS*En*2;
    bf16* AO    = (bf16*)ws; ws += nBS*En*2;

    int n4 = (int)(nBS*En/4);
    cvt_f32_to_bf16<<<(n4+255)/256, 256, 0, stream>>>(x, xb, n4);
    n4 = 3*En*En/4;
    cvt_f32_to_bf16<<<(n4+255)/256, 256, 0, stream>>>(Wqkv, wqkvb, n4);
    n4 = En*En/4;
    cvt_f32_to_bf16<<<(n4+255)/256, 256, 0, stream>>>(Wo, wob, n4);

    gemm_bt<0><<<dim3(3*En/128, nBS/128), 256, 0, stream>>>(
        xb, wqkvb, (int)nBS, 3*En, En, Qb, Kb, Vb, nullptr, nullptr);

    attn_fwd<<<dim3(Bn*Hn, Sn/256), 512, 0, stream>>>(Qb, Kb, Vb, AO);

    gemm_bt<1><<<dim3(En/128, nBS/128), 256, 0, stream>>>(
        AO, wob, (int)nBS, En, En, nullptr, nullptr, nullptr, out, bo);
}

// Round 3
// 197.090 us; speedup vs baseline: 2.5732x; 1.0427x over previous
//
#include <hip/hip_runtime.h>
#include <stdint.h>

#define Bn 4
#define Sn 2048
#define En 1024
#define Hn 16
#define HDn 64

typedef __bf16 bf16;
typedef __bf16 bf16x4 __attribute__((ext_vector_type(4)));
typedef __bf16 bf16x8 __attribute__((ext_vector_type(8)));
typedef float  f32x4  __attribute__((ext_vector_type(4)));
typedef float  f32x16 __attribute__((ext_vector_type(16)));
typedef uint32_t u32x4 __attribute__((ext_vector_type(4)));

// async global->LDS, 16B per lane, dest = wave-uniform base + lane*16
#define GLDS(gp, lp) __builtin_amdgcn_global_load_lds( \
    (const __attribute__((address_space(1))) void*)(gp), \
    (__attribute__((address_space(3))) void*)(lp), 16, 0, 0)

#define BAR() __builtin_amdgcn_s_barrier()
#define WLG() do { asm volatile("s_waitcnt lgkmcnt(0)" ::: "memory"); \
                   __builtin_amdgcn_sched_barrier(0); } while (0)
#define WVM4() asm volatile("s_waitcnt vmcnt(4)" ::: "memory")

__global__ __launch_bounds__(256) void cvt_f32_to_bf16(
    const float* __restrict__ in, bf16* __restrict__ out, int n4)
{
    int i = blockIdx.x * 256 + threadIdx.x;
    if (i >= n4) return;
    float4 f = reinterpret_cast<const float4*>(in)[i];
    bf16x4 o;
    o[0] = (bf16)f.x; o[1] = (bf16)f.y; o[2] = (bf16)f.z; o[3] = (bf16)f.w;
    reinterpret_cast<bf16x4*>(out)[i] = o;
}

// ---------------------------------------------------------------------------
// 256x256 8-phase GEMM (C = A * Bw^T), bf16 in fp32 accum. MODE0: QKV scatter.
// 8 waves (2M x 4N), per-wave 128x64 output, BK=64, 2 K-tiles per iteration.
// LDS: 2 dbuf x (256x64) x {A,B} = 128 KiB. Reads XOR-swizzled (chunk ^= row&7),
// GLDS writes linear with inverse-swizzled global source.
// Prefetch map (iteration i, tiles t=2i in buf0 / t+1 in buf1):
//   ph1: A0(t+1)->buf1   ph2: A1(t+1)->buf1   (buf1.A last read ph5/ph7 prev iter)
//   ph3: B0(t+2)->buf0   ph4: B1(t+2)->buf0   (buf0.B last read ph2 this iter)
//   ph5: A0(t+2)->buf0   ph6: A1(t+2)->buf0   (buf0.A last read ph3 this iter)
//   ph7: B0(t+3)->buf1   ph8: B1(t+3)->buf1   (buf1.B last read ph6 this iter)
// Every GLDS >= 1 full phase (2 barriers) after its region's last ds_read.
// vmcnt(4) @ ph4: drains A(t+1)+older (4 left = ph3/4 B) before ph5 reads buf1.
// vmcnt(4) @ ph8: drains A(t+2),B(t+2)    (4 left = ph7/8 B) before next ph1.
// ---------------------------------------------------------------------------
template<int MODE>
__global__ __launch_bounds__(512, 2) void gemm256(
    const bf16* __restrict__ Ag, const bf16* __restrict__ Bw,
    int M, int N, int K,
    bf16* __restrict__ q_out, bf16* __restrict__ k_out, bf16* __restrict__ v_out,
    float* __restrict__ c_out, const float* __restrict__ bias)
{
    __shared__ __align__(16) bf16 lA[2 * 256 * 64];
    __shared__ __align__(16) bf16 lB[2 * 256 * 64];

    const int tid  = threadIdx.x;
    const int lane = tid & 63;
    const int w    = tid >> 6;
    const int wm = w >> 2, wn = w & 3;
    const int lr = lane & 15, lg = lane >> 4;
    const int m0 = blockIdx.y * 256;
    const int n0 = blockIdx.x * 256;
    const int NT = K >> 6;
    const int niter = NT >> 1;

    const int srow = tid >> 3;                         // staging row 0..63
    const int sck  = (tid & 7) ^ ((tid >> 3) & 7);     // inverse-swizzled src chunk

    f32x4 acc[8][4] = {};

    auto stageA = [&](int t, int half) {
        const int ts = t < NT ? t : NT - 1;
        bf16* Ld = lA + ((t & 1) ? 16384 : 0) + (half*128 + w*8) * 64;
        const bf16* S = Ag + (size_t)(m0 + half*128 + srow) * K + ts*64 + sck*8;
        GLDS(S, Ld);
        GLDS(S + (size_t)64 * K, Ld + 64 * 64);
    };
    auto stageB = [&](int t, int half) {
        const int ts = t < NT ? t : NT - 1;
        bf16* Ld = lB + ((t & 1) ? 16384 : 0) + (half*128 + w*8) * 64;
        const bf16* S = Bw + (size_t)(n0 + half*128 + srow) * K + ts*64 + sck*8;
        GLDS(S, Ld);
        GLDS(S + (size_t)64 * K, Ld + 64 * 64);
    };
    auto ldA4 = [&](bf16x8 (&a)[4][2], const bf16* Lb, int qm) {
        #pragma unroll
        for (int ii = 0; ii < 4; ++ii) {
            const bf16* p = Lb + (wm*128 + qm*64 + ii*16 + lr) * 64;
            #pragma unroll
            for (int kk = 0; kk < 2; ++kk)
                a[ii][kk] = *reinterpret_cast<const bf16x8*>(p + (((kk << 2) + lg) ^ (lr & 7)) * 8);
        }
    };
    auto ldB2 = [&](bf16x8 (&b)[2][2], const bf16* Lb, int qn) {
        #pragma unroll
        for (int j = 0; j < 2; ++j) {
            const bf16* p = Lb + (wn*64 + qn*32 + j*16 + lr) * 64;
            #pragma unroll
            for (int kk = 0; kk < 2; ++kk)
                b[j][kk] = *reinterpret_cast<const bf16x8*>(p + (((kk << 2) + lg) ^ (lr & 7)) * 8);
        }
    };
    auto mmac = [&](const bf16x8 (&a)[4][2], const bf16x8 (&b)[2][2], int qm, int qn) {
        __builtin_amdgcn_s_setprio(1);
        #pragma unroll
        for (int ii = 0; ii < 4; ++ii)
            #pragma unroll
            for (int j = 0; j < 2; ++j)
                #pragma unroll
                for (int kk = 0; kk < 2; ++kk)
                    acc[qm*4 + ii][qn*2 + j] = __builtin_amdgcn_mfma_f32_16x16x32_bf16(
                        a[ii][kk], b[j][kk], acc[qm*4 + ii][qn*2 + j], 0, 0, 0);
        __builtin_amdgcn_s_setprio(0);
    };

    // prologue: tile0 (A+B) + tile1 B; wait tile0 landed (4 outstanding = tile1 B)
    stageA(0, 0); stageA(0, 1); stageB(0, 0); stageB(0, 1);
    stageB(1, 0); stageB(1, 1);
    WVM4(); BAR();

    const bf16* A0 = lA;          const bf16* A1 = lA + 16384;
    const bf16* B0l = lB;         const bf16* B1l = lB + 16384;
    bf16x8 a[4][2], b0[2][2], b1[2][2];

    for (int i = 0; i < niter; ++i) {
        const int t = 2 * i;
        // ph1
        ldA4(a, A0, 0); ldB2(b0, B0l, 0);
        stageA(t + 1, 0);
        BAR(); WLG();
        mmac(a, b0, 0, 0);
        BAR();
        // ph2
        ldB2(b1, B0l, 1);
        stageA(t + 1, 1);
        BAR(); WLG();
        mmac(a, b1, 0, 1);
        BAR();
        // ph3
        ldA4(a, A0, 1);
        stageB(t + 2, 0);
        BAR(); WLG();
        mmac(a, b0, 1, 0);
        BAR();
        // ph4
        stageB(t + 2, 1);
        WVM4(); BAR();
        mmac(a, b1, 1, 1);
        BAR();
        // ph5
        ldA4(a, A1, 0); ldB2(b0, B1l, 0);
        stageA(t + 2, 0);
        BAR(); WLG();
        mmac(a, b0, 0, 0);
        BAR();
        // ph6
        ldB2(b1, B1l, 1);
        stageA(t + 2, 1);
        BAR(); WLG();
        mmac(a, b1, 0, 1);
        BAR();
        // ph7
        ldA4(a, A1, 1);
        stageB(t + 3, 0);
        BAR(); WLG();
        mmac(a, b0, 1, 0);
        BAR();
        // ph8
        stageB(t + 3, 1);
        WVM4(); BAR();
        mmac(a, b1, 1, 1);
        BAR();
    }

    #pragma unroll
    for (int ii = 0; ii < 8; ++ii) {
        #pragma unroll
        for (int j = 0; j < 4; ++j) {
            const int colb = n0 + wn*64 + j*16 + lr;
            #pragma unroll
            for (int r = 0; r < 4; ++r) {
                const int rowb = m0 + wm*128 + ii*16 + lg*4 + r;
                const float v = acc[ii][j][r];
                if (MODE == 0) {
                    const int bb = rowb >> 11, s = rowb & (Sn - 1);
                    const int h = colb / 192, rr = colb - h*192;
                    const int wq = rr >> 6, hd = rr & 63;
                    const size_t off = (((size_t)(bb*Hn + h))*Sn + s)*HDn + hd;
                    const bf16 bv = (bf16)v;
                    if (wq == 0)      q_out[off] = bv;
                    else if (wq == 1) k_out[off] = bv;
                    else              v_out[off] = bv;
                } else {
                    c_out[(size_t)rowb*N + colb] = v + bias[colb];
                }
            }
        }
    }
}

// C = A (MxK) * B^T, 128^2 m97 structure. Used for the Wo projection (MODE 1).
template<int MODE>
__global__ __launch_bounds__(256) void gemm_bt(
    const bf16* __restrict__ A, const bf16* __restrict__ Bw,
    int M, int N, int K,
    bf16* __restrict__ q_out, bf16* __restrict__ k_out, bf16* __restrict__ v_out,
    float* __restrict__ c_out, const float* __restrict__ bias)
{
    __shared__ bf16 lA[128*64];
    __shared__ bf16 lB[128*64];
    const int tid  = threadIdx.x;
    const int lane = tid & 63;
    const int wv   = tid >> 6;
    const int wm = wv >> 1, wn = wv & 1;
    const int m0 = blockIdx.y * 128;
    const int n0 = blockIdx.x * 128;
    const int lr = lane & 15, lg = lane >> 4;

    f32x4 acc[4][4] = {};

    const int rowA = wv*8 + (lane>>3);
    const int col8 = (lane&7)*8;

    for (int k0 = 0; k0 < K; k0 += 64) {
        #pragma unroll
        for (int c = 0; c < 4; ++c) {
            int row = c*32 + rowA;
            GLDS(A  + (size_t)(m0+row)*K + k0 + col8, lA + (c*32 + wv*8)*64);
            GLDS(Bw + (size_t)(n0+row)*K + k0 + col8, lB + (c*32 + wv*8)*64);
        }
        __syncthreads();
        #pragma unroll
        for (int kk = 0; kk < 64; kk += 32) {
            bf16x8 af[4], bfv[4];
            #pragma unroll
            for (int i = 0; i < 4; ++i)
                af[i] = *reinterpret_cast<const bf16x8*>(lA + (wm*64 + i*16 + lr)*64 + kk + lg*8);
            #pragma unroll
            for (int j = 0; j < 4; ++j)
                bfv[j] = *reinterpret_cast<const bf16x8*>(lB + (wn*64 + j*16 + lr)*64 + kk + lg*8);
            #pragma unroll
            for (int i = 0; i < 4; ++i)
                #pragma unroll
                for (int j = 0; j < 4; ++j)
                    acc[i][j] = __builtin_amdgcn_mfma_f32_16x16x32_bf16(af[i], bfv[j], acc[i][j], 0, 0, 0);
        }
        __syncthreads();
    }

    #pragma unroll
    for (int i = 0; i < 4; ++i) {
        #pragma unroll
        for (int j = 0; j < 4; ++j) {
            const int colb = n0 + wn*64 + j*16 + lr;
            #pragma unroll
            for (int r = 0; r < 4; ++r) {
                const int rowb = m0 + wm*64 + i*16 + lg*4 + r;
                const float v = acc[i][j][r];
                if (MODE == 0) {
                    const int b = rowb >> 11, s = rowb & (Sn-1);
                    const int h = colb / 192, rr = colb - h*192;
                    const int wq = rr >> 6, hd = rr & 63;
                    const size_t off = (((size_t)(b*Hn + h))*Sn + s)*HDn + hd;
                    const bf16 bv = (bf16)v;
                    if (wq == 0)      q_out[off] = bv;
                    else if (wq == 1) k_out[off] = bv;
                    else              v_out[off] = bv;
                } else {
                    c_out[(size_t)rowb*N + colb] = v + bias[colb];
                }
            }
        }
    }
}

static __device__ __forceinline__ uint32_t pkbf(float lo, float hi)
{
    uint16_t a = __builtin_bit_cast(uint16_t, (bf16)lo);
    uint16_t b = __builtin_bit_cast(uint16_t, (bf16)hi);
    return (uint32_t)a | ((uint32_t)b << 16);
}

// Flash attention, causal. 8 waves x 32 queries, KV tiles of 64 keys.
// Swapped QK^T; softmax in exp2-scaled domain (one FMA + v_exp per element);
// defer-max (T13, THR=8) skips the O-rescale on most tiles.
__global__ __launch_bounds__(512) void attn_fwd(
    const bf16* __restrict__ Q, const bf16* __restrict__ Kg, const bf16* __restrict__ Vg,
    bf16* __restrict__ O)
{
    __shared__ __align__(16) bf16 Kl[64*64];
    __shared__ __align__(16) bf16 Vt[64*64];

    const int tid  = threadIdx.x;
    const int lane = tid & 63;
    const int w    = tid >> 6;
    const int col  = lane & 31;
    const int hv   = lane >> 5;
    const int bh   = blockIdx.x;
    const int qb   = (gridDim.y - 1) - blockIdx.y;
    const int q0w  = qb*256 + w*32;
    const int qg   = q0w + col;

    const bf16* Qb = Q  + (size_t)bh*Sn*HDn;
    const bf16* Kb = Kg + (size_t)bh*Sn*HDn;
    const bf16* Vb = Vg + (size_t)bh*Sn*HDn;

    bf16x8 aq[4];
    #pragma unroll
    for (int ks = 0; ks < 4; ++ks)
        aq[ks] = *reinterpret_cast<const bf16x8*>(Qb + (size_t)qg*HDn + ks*16 + hv*8);

    f32x16 ov[2] = {};
    const float S2 = 0.18033688011112042f;   // 0.125 * log2(e)
    float m_run = -1e30f, l_run = 0.f;       // in exp2-scaled domain

    const int srow = tid >> 3;
    const int scol = tid & 7;
    const int ksw  = scol ^ (srow & 7);

    const int nkt = 4*(qb+1);
    for (int kt = 0; kt < nkt; ++kt) {
        const int k0 = kt*64;
        __syncthreads();
        GLDS(Kb + (size_t)(k0 + srow)*HDn + ksw*8, Kl + (size_t)w*512);
        {
            bf16x8 vv = *reinterpret_cast<const bf16x8*>(Vb + (size_t)(k0 + srow)*HDn + scol*8);
            #pragma unroll
            for (int j = 0; j < 8; ++j) {
                const int chunk = (scol*8 + j)*8 + ((srow>>3) ^ scol);
                Vt[chunk*8 + (srow&7)] = vv[j];
            }
        }
        __syncthreads();

        if (k0 > q0w + 31) continue;

        f32x16 st[2] = {};
        #pragma unroll
        for (int kb = 0; kb < 2; ++kb) {
            const int key = kb*32 + col;
            #pragma unroll
            for (int ks = 0; ks < 4; ++ks) {
                const int chunk = key*8 + ((ks*2 + hv) ^ (key & 7));
                bf16x8 kf = *reinterpret_cast<const bf16x8*>(Kl + chunk*8);
                st[kb] = __builtin_amdgcn_mfma_f32_32x32x16_bf16(kf, aq[ks], st[kb], 0, 0, 0);
            }
        }

        if (k0 + 63 > q0w) {
            #pragma unroll
            for (int kb = 0; kb < 2; ++kb)
                #pragma unroll
                for (int r = 0; r < 16; ++r) {
                    const int keyg = k0 + kb*32 + (r&3) + 8*(r>>2) + 4*hv;
                    if (keyg > qg) st[kb][r] = -1e30f;
                }
        }

        // max over raw scores (S2 > 0 commutes with max)
        float mx = st[0][0];
        #pragma unroll
        for (int kb = 0; kb < 2; ++kb)
            #pragma unroll
            for (int r = 0; r < 16; ++r)
                mx = fmaxf(mx, st[kb][r]);
        mx = fmaxf(mx, __shfl_xor(mx, 32));
        const float smax2 = mx * S2;

        // defer-max: rescale only when max grew by > 8 (in log2 units)
        if (!__all(smax2 - m_run <= 8.0f)) {
            const float mn = fmaxf(m_run, smax2);
            const float fr = exp2f(m_run - mn);
            l_run *= fr;
            #pragma unroll
            for (int hb = 0; hb < 2; ++hb)
                #pragma unroll
                for (int r = 0; r < 16; ++r)
                    ov[hb][r] *= fr;
            m_run = mn;
        }

        uint32_t wpk[2][8];
        float sum = 0.f;
        #pragma unroll
        for (int kb = 0; kb < 2; ++kb)
            #pragma unroll
            for (int i = 0; i < 8; ++i) {
                const float e0 = exp2f(fmaf(st[kb][2*i],   S2, -m_run));
                const float e1 = exp2f(fmaf(st[kb][2*i+1], S2, -m_run));
                sum += e0 + e1;
                wpk[kb][i] = pkbf(e0, e1);
            }
        l_run += sum;

        #pragma unroll
        for (int s = 0; s < 4; ++s) {
            const int kb = s >> 1, ls = s & 1;
            const uint32_t send0 = hv ? wpk[kb][4*ls+0] : wpk[kb][4*ls+2];
            const uint32_t send1 = hv ? wpk[kb][4*ls+1] : wpk[kb][4*ls+3];
            const uint32_t keep0 = hv ? wpk[kb][4*ls+2] : wpk[kb][4*ls+0];
            const uint32_t keep1 = hv ? wpk[kb][4*ls+3] : wpk[kb][4*ls+1];
            const uint32_t r0 = (uint32_t)__shfl_xor((int)send0, 32);
            const uint32_t r1 = (uint32_t)__shfl_xor((int)send1, 32);
            u32x4 pwv = { hv ? r0 : keep0, hv ? r1 : keep1,
                          hv ? keep0 : r0, hv ? keep1 : r1 };
            bf16x8 pB = __builtin_bit_cast(bf16x8, pwv);
            #pragma unroll
            for (int hb = 0; hb < 2; ++hb) {
                const int hd = hb*32 + col;
                const int chunk = hd*8 + ((s*2 + hv) ^ ((hd>>3) & 7));
                bf16x8 vf = *reinterpret_cast<const bf16x8*>(Vt + chunk*8);
                ov[hb] = __builtin_amdgcn_mfma_f32_32x32x16_bf16(vf, pB, ov[hb], 0, 0, 0);
            }
        }
    }

    const float lt  = l_run + __shfl_xor(l_run, 32);
    const float inv = 1.0f / lt;
    const int b = bh >> 4, hh = bh & 15;
    bf16* Ob = O + ((size_t)(b*Sn + qg))*En + hh*HDn;
    #pragma unroll
    for (int hb = 0; hb < 2; ++hb)
        #pragma unroll
        for (int g = 0; g < 4; ++g) {
            bf16x4 o4;
            #pragma unroll
            for (int r4 = 0; r4 < 4; ++r4)
                o4[r4] = (bf16)(ov[hb][g*4 + r4] * inv);
            *reinterpret_cast<bf16x4*>(Ob + hb*32 + g*8 + 4*hv) = o4;
        }
}

extern "C" void kernel_launch(void* const* d_in, const int* in_sizes, int n_in,
                              void* d_out, int out_size, void* d_ws, size_t ws_size,
                              hipStream_t stream)
{
    (void)in_sizes; (void)n_in; (void)out_size; (void)ws_size;
    const float* x    = (const float*)d_in[0];
    const float* Wqkv = (const float*)d_in[1];
    const float* Wo   = (const float*)d_in[2];
    const float* bo   = (const float*)d_in[3];
    float* out = (float*)d_out;

    const size_t nBS = (size_t)Bn*Sn;
    char* ws = (char*)d_ws;
    bf16* xb    = (bf16*)ws; ws += nBS*En*2;
    bf16* wqkvb = (bf16*)ws; ws += (size_t)3*En*En*2;
    bf16* wob   = (bf16*)ws; ws += (size_t)En*En*2;
    bf16* Qb    = (bf16*)ws; ws += nBS*En*2;
    bf16* Kb    = (bf16*)ws; ws += nBS*En*2;
    bf16* Vb    = (bf16*)ws; ws += nBS*En*2;
    bf16* AO    = (bf16*)ws; ws += nBS*En*2;

    int n4 = (int)(nBS*En/4);
    cvt_f32_to_bf16<<<(n4+255)/256, 256, 0, stream>>>(x, xb, n4);
    n4 = 3*En*En/4;
    cvt_f32_to_bf16<<<(n4+255)/256, 256, 0, stream>>>(Wqkv, wqkvb, n4);
    n4 = En*En/4;
    cvt_f32_to_bf16<<<(n4+255)/256, 256, 0, stream>>>(Wo, wob, n4);

    gemm256<0><<<dim3(3*En/256, nBS/256), 512, 0, stream>>>(
        xb, wqkvb, (int)nBS, 3*En, En, Qb, Kb, Vb, nullptr, nullptr);

    attn_fwd<<<dim3(Bn*Hn, Sn/256), 512, 0, stream>>>(Qb, Kb, Vb, AO);

    gemm_bt<1><<<dim3(En/128, nBS/128), 256, 0, stream>>>(
        AO, wob, (int)nBS, En, En, nullptr, nullptr, nullptr, out, bo);
}